// Round 4
// baseline (791.951 us; speedup 1.0000x reference)
//
#include <hip/hip_runtime.h>
#include <cstdint>

// HashGrid encode: N pts x 16 levels x F=2, T=2^19 entries/level.
// Thread-per-point, all levels unrolled, nontemporal 16B output stores.

#define T_MASK 0x7FFFFu
#define PI1 0x9E3779B1u   // -1640531535 as int32
#define PI2 805459861u

typedef float floatx4 __attribute__((ext_vector_type(4)));

__global__ __launch_bounds__(256) void hashgrid_kernel(
    const float* __restrict__ xy,
    const float* __restrict__ tables,
    float* __restrict__ out,
    int n_pts)
{
    int n = blockIdx.x * 256 + threadIdx.x;
    if (n >= n_pts) return;

    const float2 p = *reinterpret_cast<const float2*>(xy + 2ull * n);
    const float u = p.x * 0.5f + 0.5f;
    const float v = p.y * 0.5f + 0.5f;

    // res[l] = (float)int(16 * 1.38**l)
    const float res[16] = {16.f, 22.f, 30.f, 42.f, 58.f, 80.f, 110.f, 152.f,
                           210.f, 290.f, 400.f, 553.f, 763.f, 1053.f, 1453.f, 2005.f};

    float o[32];

#pragma unroll
    for (int l = 0; l < 16; ++l) {
        const float sx = u * res[l];
        const float sy = v * res[l];
        const float flx = floorf(sx);
        const float fly = floorf(sy);
        const float fx = sx - flx;
        const float fy = sy - fly;
        const int ix = (int)flx;
        const int iy = (int)fly;

        // (cx)*PI1 and (cx+1)*PI1 = hx0 + PI1 ; same for y with PI2.
        const uint32_t hx0 = (uint32_t)ix * PI1;
        const uint32_t hx1 = hx0 + PI1;
        const uint32_t hy0 = (uint32_t)iy * PI2;
        const uint32_t hy1 = hy0 + PI2;

        // floor-mod by 2^19 == bitwise AND on two's-complement bits; abs is no-op.
        const float2* __restrict__ tb =
            reinterpret_cast<const float2*>(tables) + (size_t)l * 524288u;
        const float2 c00 = tb[(hx0 ^ hy0) & T_MASK];
        const float2 c10 = tb[(hx1 ^ hy0) & T_MASK];
        const float2 c01 = tb[(hx0 ^ hy1) & T_MASK];
        const float2 c11 = tb[(hx1 ^ hy1) & T_MASK];

        const float w00 = (1.f - fx) * (1.f - fy);
        const float w10 = fx * (1.f - fy);
        const float w01 = (1.f - fx) * fy;
        const float w11 = fx * fy;

        o[2 * l]     = w00 * c00.x + w10 * c10.x + w01 * c01.x + w11 * c11.x;
        o[2 * l + 1] = w00 * c00.y + w10 * c10.y + w01 * c01.y + w11 * c11.y;
    }

    // 32 floats = 8 x 16B nontemporal stores (don't thrash L2 holding tables).
    floatx4* __restrict__ o4 = reinterpret_cast<floatx4*>(out + (size_t)n * 32u);
#pragma unroll
    for (int j = 0; j < 8; ++j) {
        floatx4 val = *reinterpret_cast<floatx4*>(&o[4 * j]);
        __builtin_nontemporal_store(val, o4 + j);
    }
}

extern "C" void kernel_launch(void* const* d_in, const int* in_sizes, int n_in,
                              void* d_out, int out_size, void* d_ws, size_t ws_size,
                              hipStream_t stream) {
    const float* xy     = (const float*)d_in[0];
    const float* tables = (const float*)d_in[1];
    float* out          = (float*)d_out;
    const int n_pts = in_sizes[0] / 2;  // 1048576

    const int block = 256;
    const int grid = (n_pts + block - 1) / block;
    hashgrid_kernel<<<grid, block, 0, stream>>>(xy, tables, out, n_pts);
}

// Round 12
// 574.011 us; speedup vs baseline: 1.3797x; 1.3797x over previous
//
#include <hip/hip_runtime.h>
#include <cstdint>

#define T_MASK 0x7FFFFu
#define PI1 0x9E3779B1u   // -1640531535 as int32
#define PI2 805459861u
#define NPTS 1048576

typedef float floatx4 __attribute__((ext_vector_type(4)));
typedef float floatx2 __attribute__((ext_vector_type(2)));

__device__ __forceinline__ floatx2 corner_blend(const float* __restrict__ tb,
                                                float u, float v, float res) {
    const float sx = u * res, sy = v * res;
    const float flx = floorf(sx), fly = floorf(sy);
    const float fx = sx - flx, fy = sy - fly;
    const uint32_t hx0 = (uint32_t)(int)flx * PI1, hx1 = hx0 + PI1;
    const uint32_t hy0 = (uint32_t)(int)fly * PI2, hy1 = hy0 + PI2;
    const floatx2* __restrict__ t2 = (const floatx2*)tb;
    const floatx2 c00 = t2[(hx0 ^ hy0) & T_MASK];
    const floatx2 c10 = t2[(hx1 ^ hy0) & T_MASK];
    const floatx2 c01 = t2[(hx0 ^ hy1) & T_MASK];
    const floatx2 c11 = t2[(hx1 ^ hy1) & T_MASK];
    const float w00 = (1.f - fx) * (1.f - fy), w10 = fx * (1.f - fy);
    const float w01 = (1.f - fx) * fy,         w11 = fx * fy;
    floatx2 r;
    r.x = w00 * c00.x + w10 * c10.x + w01 * c01.x + w11 * c11.x;
    r.y = w00 * c00.y + w10 * c10.y + w01 * c01.y + w11 * c11.y;
    return r;
}

// Heavy levels 12..15: one level per XCD (blockIdx%8 -> XCD round-robin).
// Each XCD's 4 MiB L2 holds exactly its level's 4 MiB table.
// 2 points/thread; results to ws level-major, NT full-line stores.
__global__ __launch_bounds__(256) void k_heavy(const float* __restrict__ xy,
                                               const float* __restrict__ tables,
                                               float* __restrict__ ws) {
    const float resH[4] = {763.f, 1053.f, 1453.f, 2005.f};
    const uint32_t b = blockIdx.x;
    const uint32_t xcd = b & 7u;
    const uint32_t li = xcd & 3u;        // level 12+li
    const uint32_t half = xcd >> 2;      // which half of the points
    const uint32_t c = b >> 3u;
    const uint32_t p0 = half * (NPTS / 2u) + c * 512u + threadIdx.x * 2u;

    const floatx4 pxy = __builtin_nontemporal_load(
        (const floatx4*)(xy + 2ull * p0));
    const float* __restrict__ tb = tables + (size_t)(12u + li) * 1048576u;
    const float res = resH[li];

    const floatx2 r0 = corner_blend(tb, pxy.x * 0.5f + 0.5f, pxy.y * 0.5f + 0.5f, res);
    const floatx2 r1 = corner_blend(tb, pxy.z * 0.5f + 0.5f, pxy.w * 0.5f + 0.5f, res);
    floatx4 o;
    o.x = r0.x; o.y = r0.y; o.z = r1.x; o.w = r1.y;
    __builtin_nontemporal_store(o,
        (floatx4*)(ws + (size_t)li * (2u * NPTS) + 2ull * p0));
}

// Light levels 0..11 (hot footprint ~4 MB -> L2 resident) + merge ws,
// LDS-transposed fully-coalesced NT output stores (no write amp, no L2 pollution).
__global__ __launch_bounds__(256) void k_light(const float* __restrict__ xy,
                                               const float* __restrict__ tables,
                                               const float* __restrict__ ws,
                                               float* __restrict__ out) {
    __shared__ float sm[4 * 2048];  // 4 waves x 64 rows x 32 floats (XOR-swizzled cols)
    const float resL[12] = {16.f, 22.f, 30.f, 42.f, 58.f, 80.f, 110.f, 152.f,
                            210.f, 290.f, 400.f, 553.f};
    const uint32_t n = blockIdx.x * 256u + threadIdx.x;

    const floatx2 p = __builtin_nontemporal_load((const floatx2*)(xy + 2ull * n));
    const float u = p.x * 0.5f + 0.5f, v = p.y * 0.5f + 0.5f;

    float o[32];
#pragma unroll
    for (int l = 0; l < 12; ++l) {
        const floatx2 r = corner_blend(tables + (size_t)l * 1048576u, u, v, resL[l]);
        o[2 * l] = r.x; o[2 * l + 1] = r.y;
    }
#pragma unroll
    for (int li = 0; li < 4; ++li) {
        const floatx2 r = __builtin_nontemporal_load(
            (const floatx2*)(ws + (size_t)li * (2u * NPTS) + 2ull * n));
        o[24 + 2 * li] = r.x; o[25 + 2 * li] = r.y;
    }

    const uint32_t w = threadIdx.x >> 6, lane = threadIdx.x & 63u;
    float* ms = sm + w * 2048u;
    // write row `lane`, chunk j at column j^(lane&7)  (16B-aligned, bank-spread)
#pragma unroll
    for (int j = 0; j < 8; ++j)
        *(floatx4*)(ms + lane * 32u + 4u * (j ^ (lane & 7u))) =
            *(const floatx4*)(o + 4 * j);
    __syncthreads();

    const size_t obase = ((size_t)blockIdx.x * 256u + w * 64u) * 32u;
#pragma unroll
    for (int k = 0; k < 8; ++k) {
        const uint32_t t = k * 8u + (lane >> 3);      // source row
        const uint32_t jc = (lane & 7u) ^ (t & 7u);   // swizzled column
        const floatx4 vv = *(const floatx4*)(ms + t * 32u + 4u * jc);
        __builtin_nontemporal_store(vv,
            (floatx4*)(out + obase + (size_t)(k * 256u + lane * 4u)));
    }
}

// Fallback (unexpected sizes / tiny ws): round-4 kernel with cached stores.
__global__ __launch_bounds__(256) void k_fallback(const float* __restrict__ xy,
                                                  const float* __restrict__ tables,
                                                  float* __restrict__ out, int n_pts) {
    int n = blockIdx.x * 256 + threadIdx.x;
    if (n >= n_pts) return;
    const float2 p = *reinterpret_cast<const float2*>(xy + 2ull * n);
    const float u = p.x * 0.5f + 0.5f, v = p.y * 0.5f + 0.5f;
    const float res[16] = {16.f, 22.f, 30.f, 42.f, 58.f, 80.f, 110.f, 152.f,
                           210.f, 290.f, 400.f, 553.f, 763.f, 1053.f, 1453.f, 2005.f};
    float o[32];
#pragma unroll
    for (int l = 0; l < 16; ++l) {
        const floatx2 r = corner_blend(tables + (size_t)l * 1048576u, u, v, res[l]);
        o[2 * l] = r.x; o[2 * l + 1] = r.y;
    }
    floatx4* o4 = reinterpret_cast<floatx4*>(out + (size_t)n * 32u);
#pragma unroll
    for (int j = 0; j < 8; ++j) o4[j] = *(const floatx4*)(&o[4 * j]);
}

extern "C" void kernel_launch(void* const* d_in, const int* in_sizes, int n_in,
                              void* d_out, int out_size, void* d_ws, size_t ws_size,
                              hipStream_t stream) {
    const float* xy     = (const float*)d_in[0];
    const float* tables = (const float*)d_in[1];
    float* out          = (float*)d_out;
    const int n_pts = in_sizes[0] / 2;

    const size_t ws_need = 4ull * NPTS * 2ull * sizeof(float);  // 32 MB
    if (n_pts == NPTS && ws_size >= ws_need) {
        float* ws = (float*)d_ws;
        // heavy: 4 levels x 2 XCD-halves x 1024 blocks
        k_heavy<<<8192, 256, 0, stream>>>(xy, tables, ws);
        // light + merge: 1M/256 blocks
        k_light<<<NPTS / 256, 256, 0, stream>>>(xy, tables, ws, out);
    } else {
        k_fallback<<<(n_pts + 255) / 256, 256, 0, stream>>>(xy, tables, out, n_pts);
    }
}

// Round 13
// 481.917 us; speedup vs baseline: 1.6433x; 1.1911x over previous
//
#include <hip/hip_runtime.h>
#include <cstdint>

#define T_MASK 0x7FFFFu
#define PI1 0x9E3779B1u   // -1640531535 as int32
#define PI2 805459861u
#define NPTS 1048576

typedef float floatx4 __attribute__((ext_vector_type(4)));
typedef float floatx2 __attribute__((ext_vector_type(2)));

__device__ __forceinline__ float res_of(int l) {
    const float r[16] = {16.f, 22.f, 30.f, 42.f, 58.f, 80.f, 110.f, 152.f,
                         210.f, 290.f, 400.f, 553.f, 763.f, 1053.f, 1453.f, 2005.f};
    return r[l];
}

__device__ __forceinline__ floatx2 corner_blend(const float* __restrict__ tb,
                                                float u, float v, float res) {
    const float sx = u * res, sy = v * res;
    const float flx = floorf(sx), fly = floorf(sy);
    const float fx = sx - flx, fy = sy - fly;
    const uint32_t hx0 = (uint32_t)(int)flx * PI1, hx1 = hx0 + PI1;
    const uint32_t hy0 = (uint32_t)(int)fly * PI2, hy1 = hy0 + PI2;
    const floatx2* __restrict__ t2 = (const floatx2*)tb;
    const floatx2 c00 = t2[(hx0 ^ hy0) & T_MASK];
    const floatx2 c10 = t2[(hx1 ^ hy0) & T_MASK];
    const floatx2 c01 = t2[(hx0 ^ hy1) & T_MASK];
    const floatx2 c11 = t2[(hx1 ^ hy1) & T_MASK];
    const float w00 = (1.f - fx) * (1.f - fy), w10 = fx * (1.f - fy);
    const float w01 = (1.f - fx) * fy,         w11 = fx * fy;
    floatx2 r;
    r.x = w00 * c00.x + w10 * c10.x + w01 * c01.x + w11 * c11.x;
    r.y = w00 * c00.y + w10 * c10.y + w01 * c01.y + w11 * c11.y;
    return r;
}

// One level per dispatch: device-wide temporal isolation => every XCD's L2
// caches ONLY this level's table (<= 4 MiB, fits). xy read + ws write are
// nontemporal full-line streams (no L2 pollution, no write amp).
template<int L, int SLOT>
__global__ __launch_bounds__(256) void k_phase(const float* __restrict__ xy,
                                               const float* __restrict__ tables,
                                               float* __restrict__ ws) {
    const uint32_t n = blockIdx.x * 256u + threadIdx.x;
    const floatx2 p = __builtin_nontemporal_load((const floatx2*)(xy + 2ull * n));
    const floatx2 r = corner_blend(tables + (size_t)L * 1048576u,
                                   p.x * 0.5f + 0.5f, p.y * 0.5f + 0.5f, res_of(L));
    __builtin_nontemporal_store(r,
        (floatx2*)(ws + (size_t)SLOT * 2097152u + 2ull * n));
}

// Compute levels 0..NIN-1 inline (combined line-footprint ~3 MB -> L2-resident,
// verified hitting in round-12 profile), merge NWS ws columns (levels NIN..15),
// transpose in LDS (XOR-swizzled), fully-coalesced NT output stores.
template<int NIN, int NWS>
__global__ __launch_bounds__(256) void k_merge(const float* __restrict__ xy,
                                               const float* __restrict__ tables,
                                               const float* __restrict__ ws,
                                               float* __restrict__ out) {
    __shared__ float sm[4 * 2048];  // 4 waves x 64 rows x 32 floats, swizzled cols
    const uint32_t n = blockIdx.x * 256u + threadIdx.x;
    const floatx2 p = __builtin_nontemporal_load((const floatx2*)(xy + 2ull * n));
    const float u = p.x * 0.5f + 0.5f, v = p.y * 0.5f + 0.5f;

    float o[32];
#pragma unroll
    for (int l = 0; l < NIN; ++l) {
        const floatx2 r = corner_blend(tables + (size_t)l * 1048576u, u, v, res_of(l));
        o[2 * l] = r.x; o[2 * l + 1] = r.y;
    }
#pragma unroll
    for (int s = 0; s < NWS; ++s) {
        const floatx2 r = __builtin_nontemporal_load(
            (const floatx2*)(ws + (size_t)s * 2097152u + 2ull * n));
        o[2 * (NIN + s)] = r.x; o[2 * (NIN + s) + 1] = r.y;
    }

    const uint32_t w = threadIdx.x >> 6, lane = threadIdx.x & 63u;
    float* ms = sm + w * 2048u;
#pragma unroll
    for (int j = 0; j < 8; ++j)
        *(floatx4*)(ms + lane * 32u + 4u * (j ^ (lane & 7u))) =
            *(const floatx4*)(o + 4 * j);
    __syncthreads();

    const size_t obase = ((size_t)blockIdx.x * 256u + w * 64u) * 32u;
#pragma unroll
    for (int k = 0; k < 8; ++k) {
        const uint32_t t = k * 8u + (lane >> 3);      // source row
        const uint32_t jc = (lane & 7u) ^ (t & 7u);   // swizzled column
        const floatx4 vv = *(const floatx4*)(ms + t * 32u + 4u * jc);
        __builtin_nontemporal_store(vv,
            (floatx4*)(out + obase + (size_t)(k * 256u + lane * 4u)));
    }
}

// Fallback (unexpected sizes / tiny ws): known-good round-4 kernel, cached stores.
__global__ __launch_bounds__(256) void k_fallback(const float* __restrict__ xy,
                                                  const float* __restrict__ tables,
                                                  float* __restrict__ out, int n_pts) {
    int n = blockIdx.x * 256 + threadIdx.x;
    if (n >= n_pts) return;
    const float2 p = *reinterpret_cast<const float2*>(xy + 2ull * n);
    const float u = p.x * 0.5f + 0.5f, v = p.y * 0.5f + 0.5f;
    float o[32];
#pragma unroll
    for (int l = 0; l < 16; ++l) {
        const floatx2 r = corner_blend(tables + (size_t)l * 1048576u, u, v, res_of(l));
        o[2 * l] = r.x; o[2 * l + 1] = r.y;
    }
    floatx4* o4 = reinterpret_cast<floatx4*>(out + (size_t)n * 32u);
#pragma unroll
    for (int j = 0; j < 8; ++j) o4[j] = *(const floatx4*)(&o[4 * j]);
}

extern "C" void kernel_launch(void* const* d_in, const int* in_sizes, int n_in,
                              void* d_out, int out_size, void* d_ws, size_t ws_size,
                              hipStream_t stream) {
    const float* xy     = (const float*)d_in[0];
    const float* tables = (const float*)d_in[1];
    float* out          = (float*)d_out;
    const int n_pts = in_sizes[0] / 2;

    const size_t slot_bytes = 2097152ull * 4ull;  // 8 MiB per level column
    const int grid = NPTS / 256;                  // 4096

    if (n_pts == NPTS && ws_size >= 9 * slot_bytes) {
        float* ws = (float*)d_ws;
        k_phase<15, 8><<<grid, 256, 0, stream>>>(xy, tables, ws);
        k_phase<14, 7><<<grid, 256, 0, stream>>>(xy, tables, ws);
        k_phase<13, 6><<<grid, 256, 0, stream>>>(xy, tables, ws);
        k_phase<12, 5><<<grid, 256, 0, stream>>>(xy, tables, ws);
        k_phase<11, 4><<<grid, 256, 0, stream>>>(xy, tables, ws);
        k_phase<10, 3><<<grid, 256, 0, stream>>>(xy, tables, ws);
        k_phase< 9, 2><<<grid, 256, 0, stream>>>(xy, tables, ws);
        k_phase< 8, 1><<<grid, 256, 0, stream>>>(xy, tables, ws);
        k_phase< 7, 0><<<grid, 256, 0, stream>>>(xy, tables, ws);
        k_merge<7, 9><<<grid, 256, 0, stream>>>(xy, tables, ws, out);
    } else if (n_pts == NPTS && ws_size >= 7 * slot_bytes) {
        float* ws = (float*)d_ws;
        k_phase<15, 6><<<grid, 256, 0, stream>>>(xy, tables, ws);
        k_phase<14, 5><<<grid, 256, 0, stream>>>(xy, tables, ws);
        k_phase<13, 4><<<grid, 256, 0, stream>>>(xy, tables, ws);
        k_phase<12, 3><<<grid, 256, 0, stream>>>(xy, tables, ws);
        k_phase<11, 2><<<grid, 256, 0, stream>>>(xy, tables, ws);
        k_phase<10, 1><<<grid, 256, 0, stream>>>(xy, tables, ws);
        k_phase< 9, 0><<<grid, 256, 0, stream>>>(xy, tables, ws);
        k_merge<9, 7><<<grid, 256, 0, stream>>>(xy, tables, ws, out);
    } else {
        k_fallback<<<(n_pts + 255) / 256, 256, 0, stream>>>(xy, tables, out, n_pts);
    }
}